// Round 5
// baseline (1124.652 us; speedup 1.0000x reference)
//
#include <hip/hip_runtime.h>
#include <hip/hip_bf16.h>
#include <hip/hip_fp16.h>

// SimpleRNN: B=64, S=2048, IN=256, H=128, OUT=3 (all fp32)
// Phase 1: xproj MFMA GEMM (same compute as r10-r13; epilogue now stores
//   xp as [t][b][h] so the scan reads one base + immediate offsets).
// Phase 2 (r14): MFMA-batched scan. grid=4 blocks x 512 thr (8 waves),
//   16 batches/block. Per step: H_new[16,128] = tanh(H @ W^T + xp_t + bias)
//   via mfma_f32_16x16x32_f16 (4 chained K-chunks), wave w owns cols
//   16w..16w+15 with W-frags = 16 VGPR/lane (r9-proven residency scale --
//   r11/r13's 64-128 reg/lane designs all spilled at VGPR=60..96).
//   h kept f16 in LDS [16][128], XOR-swizzled (byte ^= (row&7)<<4) so the
//   A-frag ds_read_b128 is bank-balanced. One LDS-only barrier per step.
//   Fragment layouts copied verbatim from the passing xproj_mfma:
//     A: row=lane&15, k=8*(lane>>4)+j ; B: col=lane&15, same k
//     C/D: col=lane&15, row=4*(lane>>4)+reg

#define RNN_B   64
#define RNN_S   2048
#define RNN_IN  256
#define RNN_H   128
#define RNN_OUT 3

typedef _Float16 half2v __attribute__((ext_vector_type(2)));
typedef _Float16 half4 __attribute__((ext_vector_type(4)));
typedef _Float16 half8 __attribute__((ext_vector_type(8)));
typedef float f32x4 __attribute__((ext_vector_type(4)));

// LDS-only barrier: drains lgkm (LDS) but NOT vmcnt, so global prefetch
// loads stay in flight across the barrier.
__device__ __forceinline__ void block_sync_lds() {
  asm volatile("s_waitcnt lgkmcnt(0)" ::: "memory");
  __builtin_amdgcn_s_barrier();
}

// ---------------------------------------------------------------------------
// Phase 1: f16 MFMA GEMM  C[M=131072, N=128] = A[M,256] * B[128,256]^T + bias
// Identical compute to r12/r13; store goes to xp[t][b][h].
// ---------------------------------------------------------------------------
#define XLOADC(SET, KC)                                                       \
  {                                                                           \
    const int _kc = (KC);                                                     \
    _Pragma("unroll")                                                         \
    for (int p = 0; p < 4; ++p) {                                             \
      const int row = lr + 32 * p;                                            \
      SET##a[p] = *(const float4*)&x[(size_t)(m0 + row) * RNN_IN + _kc + lc]; \
      SET##b[p] = *(const float4*)&Wxh[(size_t)row * RNN_IN + _kc + lc];      \
    }                                                                         \
  }

#define XSTORE(SET)                                                 \
  {                                                                 \
    _Pragma("unroll")                                               \
    for (int p = 0; p < 4; ++p) {                                   \
      const int row = lr + 32 * p;                                  \
      half4 ha, hb;                                                 \
      ha.x = (_Float16)SET##a[p].x; ha.y = (_Float16)SET##a[p].y;   \
      ha.z = (_Float16)SET##a[p].z; ha.w = (_Float16)SET##a[p].w;   \
      hb.x = (_Float16)SET##b[p].x; hb.y = (_Float16)SET##b[p].y;   \
      hb.z = (_Float16)SET##b[p].z; hb.w = (_Float16)SET##b[p].w;   \
      *(half4*)&Ash[row][lc] = ha;                                  \
      *(half4*)&Bsh[row][lc] = hb;                                  \
    }                                                               \
  }

#define XCOMPUTE()                                                  \
  {                                                                 \
    half8 af[4], bf[4];                                             \
    _Pragma("unroll")                                               \
    for (int m = 0; m < 4; ++m)                                     \
      af[m] = *(const half8*)&Ash[wr * 64 + m * 16 + fr][fk * 8];   \
    _Pragma("unroll")                                               \
    for (int n = 0; n < 4; ++n)                                     \
      bf[n] = *(const half8*)&Bsh[wc * 64 + n * 16 + fr][fk * 8];   \
    _Pragma("unroll")                                               \
    for (int m = 0; m < 4; ++m)                                     \
      _Pragma("unroll")                                             \
      for (int n = 0; n < 4; ++n)                                   \
        acc[m][n] = __builtin_amdgcn_mfma_f32_16x16x32_f16(         \
            af[m], bf[n], acc[m][n], 0, 0, 0);                      \
  }

__global__ __launch_bounds__(256, 2) void xproj_mfma(
    const float* __restrict__ x, const float* __restrict__ Wxh,
    const float* __restrict__ bxh, float* __restrict__ xp) {
  __shared__ __align__(16) _Float16 Ash[128][40];
  __shared__ __align__(16) _Float16 Bsh[128][40];

  const int tid = threadIdx.x;
  const int m0 = blockIdx.x * 128;
  const int wv = tid >> 6;
  const int lane = tid & 63;
  const int wr = wv >> 1;
  const int wc = wv & 1;
  const int fr = lane & 15;
  const int fk = lane >> 4;

  const int lr = tid >> 3;
  const int lc = (tid & 7) * 4;

  f32x4 acc[4][4];
#pragma unroll
  for (int m = 0; m < 4; ++m)
#pragma unroll
    for (int n = 0; n < 4; ++n) {
      acc[m][n][0] = 0.f; acc[m][n][1] = 0.f;
      acc[m][n][2] = 0.f; acc[m][n][3] = 0.f;
    }

  float4 Aa[4], Ab[4], Ba[4], Bb[4];
  XLOADC(A, 0)

#pragma unroll 1
  for (int kc = 0; kc < RNN_IN; kc += 64) {
    XSTORE(A)
    { const int nk = kc + 32; XLOADC(B, nk < RNN_IN ? nk : RNN_IN - 32) }
    block_sync_lds();
    XCOMPUTE()
    block_sync_lds();
    XSTORE(B)
    { const int nk = kc + 64; XLOADC(A, nk < RNN_IN ? nk : RNN_IN - 32) }
    block_sync_lds();
    XCOMPUTE()
    block_sync_lds();
  }

  float bb[4];
#pragma unroll
  for (int n = 0; n < 4; ++n) bb[n] = bxh[wc * 64 + n * 16 + fr];
#pragma unroll
  for (int m = 0; m < 4; ++m) {
    const size_t rbase = (size_t)(m0 + wr * 64 + m * 16 + 4 * fk);
#pragma unroll
    for (int reg = 0; reg < 4; ++reg) {
      const size_t grow = rbase + reg;            // global row = b*2048 + t
      const size_t bidx = grow >> 11;             // batch
      const size_t tidx = grow & 2047;            // timestep
      float* rowp = &xp[(tidx * RNN_B + bidx) * RNN_H];
#pragma unroll
      for (int n = 0; n < 4; ++n)
        rowp[wc * 64 + n * 16 + fr] = acc[m][n][reg] + bb[n];
    }
  }
}

// fast tanh: 1 - 2/(exp(2x)+1); saturates correctly at +-inf
__device__ __forceinline__ float fast_tanh(float a) {
  const float e = __expf(2.f * a);
  return 1.f - 2.f / (e + 1.f);
}

// ---------------------------------------------------------------------------
// Phase 2: MFMA-batched scan. grid = 4 blocks (16 batches each), 512 thr.
// ---------------------------------------------------------------------------

// prefetch one step's xp C-fragment (4 rows = 4 batches, this lane's col)
#define LDPX(PX, T)                                          \
  {                                                          \
    const size_t _o = (size_t)(T) * (RNN_B * RNN_H) + bl;    \
    PX.x = xq[_o];                                           \
    PX.y = xq[_o + RNN_H];                                   \
    PX.z = xq[_o + 2 * RNN_H];                               \
    PX.w = xq[_o + 3 * RNN_H];                               \
  }

#define SSTEP(CUR, NXT, PX, TNEXT)                                     \
  {                                                                    \
    const char* hb = &hls[CUR][0];                                     \
    const half8 a0 = *(const half8*)(hb + r0);                         \
    const half8 a1 = *(const half8*)(hb + r1);                         \
    const half8 a2 = *(const half8*)(hb + r2);                         \
    const half8 a3 = *(const half8*)(hb + r3);                         \
    f32x4 acc;                                                         \
    acc[0] = PX.x; acc[1] = PX.y; acc[2] = PX.z; acc[3] = PX.w;        \
    LDPX(PX, TNEXT)                                                    \
    acc = __builtin_amdgcn_mfma_f32_16x16x32_f16(a0, bw0, acc, 0,0,0); \
    acc = __builtin_amdgcn_mfma_f32_16x16x32_f16(a1, bw1, acc, 0,0,0); \
    acc = __builtin_amdgcn_mfma_f32_16x16x32_f16(a2, bw2, acc, 0,0,0); \
    acc = __builtin_amdgcn_mfma_f32_16x16x32_f16(a3, bw3, acc, 0,0,0); \
    hv0 = fast_tanh(acc[0] + bias);                                    \
    hv1 = fast_tanh(acc[1] + bias);                                    \
    hv2 = fast_tanh(acc[2] + bias);                                    \
    hv3 = fast_tanh(acc[3] + bias);                                    \
    char* hn = &hls[NXT][0];                                           \
    *(_Float16*)(hn + wo0) = (_Float16)hv0;                            \
    *(_Float16*)(hn + wo1) = (_Float16)hv1;                            \
    *(_Float16*)(hn + wo2) = (_Float16)hv2;                            \
    *(_Float16*)(hn + wo3) = (_Float16)hv3;                            \
    block_sync_lds();                                                  \
  }

__global__ __launch_bounds__(512, 2) void rnn_scan(
    const float* __restrict__ xq, const float* __restrict__ Whh,
    const float* __restrict__ bhh, const float* __restrict__ bh,
    const float* __restrict__ Wfc, const float* __restrict__ bfc,
    float* __restrict__ out) {
  const int tid = threadIdx.x;
  const int w = tid >> 6;            // wave 0..7 -> output cols 16w..16w+15
  const int lane = tid & 63;
  const int fr = lane & 15;
  const int fk = lane >> 4;
  const int gb = blockIdx.x * 16;    // batch-group base
  const int col = 16 * w + fr;       // hidden col this lane produces

  // h state, f16, [16 rows(batch)][128 cols], byte ^= ((row&7)<<4) swizzle.
  __shared__ __align__(16) char hls[2][16 * 256];  // 2 x 4 KiB
  __shared__ float hfin[16][RNN_H];                // final h (fp32) for FC

  // B-frags: W_hh rows = output cols; 4 K-chunks -> 16 VGPR total.
  half8 bw0, bw1, bw2, bw3;
  {
    const float* wrow = &Whh[(size_t)col * RNN_H];
#define LDW(c, dst)                                              \
    {                                                            \
      const float4 lo = *(const float4*)&wrow[32 * (c) + 8 * fk];     \
      const float4 hi = *(const float4*)&wrow[32 * (c) + 8 * fk + 4]; \
      half8 t;                                                   \
      t[0] = (_Float16)lo.x; t[1] = (_Float16)lo.y;              \
      t[2] = (_Float16)lo.z; t[3] = (_Float16)lo.w;              \
      t[4] = (_Float16)hi.x; t[5] = (_Float16)hi.y;              \
      t[6] = (_Float16)hi.z; t[7] = (_Float16)hi.w;              \
      dst = t;                                                   \
    }
    LDW(0, bw0) LDW(1, bw1) LDW(2, bw2) LDW(3, bw3)
  }

  const float bias = bhh[col] + bh[col];

  // A-frag read offsets (chunk c): row=fr, k=32c+8fk.. ; swizzled
  const int swz = (fr & 7) << 4;
  const int r0 = (fr * 256 + 0   + 16 * fk) ^ swz;
  const int r1 = (fr * 256 + 64  + 16 * fk) ^ swz;
  const int r2 = (fr * 256 + 128 + 16 * fk) ^ swz;
  const int r3 = (fr * 256 + 192 + 16 * fk) ^ swz;

  // C/D write offsets: row=4fk+reg, this lane's col; swizzled
#define WOFF(reg) \
  ((((4 * fk + (reg)) * 256) + col * 2) ^ (((4 * fk + (reg)) & 7) << 4))
  const int wo0 = WOFF(0);
  const int wo1 = WOFF(1);
  const int wo2 = WOFF(2);
  const int wo3 = WOFF(3);

  // zero h buffer 0 (4096 B, 512 threads x 8 B); swizzle-invariant
  {
    float2 z; z.x = 0.f; z.y = 0.f;
    ((float2*)&hls[0][0])[tid] = z;
  }
  block_sync_lds();

  // per-lane xp base: xq[t][batch gb+4fk+reg][col], reg via +128 floats
  const int bl = (gb + 4 * fk) * RNN_H + col;

  float4 px0, px1, px2, px3;
  LDPX(px0, 0) LDPX(px1, 1) LDPX(px2, 2) LDPX(px3, 3)

  float hv0 = 0.f, hv1 = 0.f, hv2 = 0.f, hv3 = 0.f;

#pragma unroll 1
  for (int t = 0; t < RNN_S; t += 4) {
    const int n0 = (t + 4 < RNN_S) ? t + 4 : RNN_S - 1;
    const int n1 = (t + 5 < RNN_S) ? t + 5 : RNN_S - 1;
    const int n2 = (t + 6 < RNN_S) ? t + 6 : RNN_S - 1;
    const int n3 = (t + 7 < RNN_S) ? t + 7 : RNN_S - 1;
    SSTEP(0, 1, px0, n0)
    SSTEP(1, 0, px1, n1)
    SSTEP(0, 1, px2, n2)
    SSTEP(1, 0, px3, n3)
  }
  // final h (fp32, un-quantized) for this lane: batches 4fk+reg, this col.
  hfin[4 * fk + 0][col] = hv0;
  hfin[4 * fk + 1][col] = hv1;
  hfin[4 * fk + 2][col] = hv2;
  hfin[4 * fk + 3][col] = hv3;
  block_sync_lds();

  // FC: 48 threads, one (batch, out) pair each; Wfc rows are L1-resident.
  if (tid < 16 * RNN_OUT) {
    const int o = tid % RNN_OUT;
    const int bb = tid / RNN_OUT;
    float s = bfc[o];
#pragma unroll 8
    for (int k = 0; k < RNN_H; ++k)
      s = fmaf(Wfc[(size_t)o * RNN_H + k], hfin[bb][k], s);
    out[(gb + bb) * RNN_OUT + o] = s;
  }
}

extern "C" void kernel_launch(void* const* d_in, const int* in_sizes, int n_in,
                              void* d_out, int out_size, void* d_ws, size_t ws_size,
                              hipStream_t stream) {
  const float* x   = (const float*)d_in[0];
  const float* Wxh = (const float*)d_in[1];
  const float* bxh = (const float*)d_in[2];
  const float* Whh = (const float*)d_in[3];
  const float* bhh = (const float*)d_in[4];
  const float* bh  = (const float*)d_in[5];
  const float* Wfc = (const float*)d_in[6];
  const float* bfc = (const float*)d_in[7];
  float* out = (float*)d_out;
  float* xp  = (float*)d_ws;  // 2048*64*128*4 = 64 MiB, layout [t][b][h]

  xproj_mfma<<<dim3((RNN_B * RNN_S) / 128), dim3(256), 0, stream>>>(x, Wxh, bxh, xp);
  rnn_scan<<<dim3(RNN_B / 16), dim3(512), 0, stream>>>(xp, Whh, bhh, bh, Wfc, bfc, out);
}